// Round 11
// baseline (296.934 us; speedup 1.0000x reference)
//
#include <hip/hip_runtime.h>
#include <stdint.h>

#define NNODES 10000
#define NEDGES 100000
#define DNODE 56
#define JTOT 1600
#define EBLK 782    // hidden-GEMM blocks (128 edges each)
#define TBLK 400    // G pre-pack blocks
#define GBLK 640    // gather blocks

typedef __attribute__((ext_vector_type(8))) short short8;
typedef __attribute__((ext_vector_type(4))) float floatx4;
typedef __attribute__((ext_vector_type(16))) float floatx16;

__device__ __forceinline__ unsigned short f2bf(float f) {
  unsigned u = __float_as_uint(f);
  u = u + 0x7fffu + ((u >> 16) & 1u);
  return (unsigned short)(u >> 16);
}
__device__ __forceinline__ float bf2f(unsigned short u) {
  return __uint_as_float(((unsigned)u) << 16);
}

__device__ __forceinline__ float mishf(float x) {
  float e = __expf(x);
  float z = 1.f + e; z = z * z;
  float t = (z - 1.f) / (z + 1.f);
  t = (x > 40.f) ? 1.f : t;
  return x * t;
}

// async 16B global -> LDS; lds base wave-uniform (HW adds lane*16)
__device__ __forceinline__ void async_ld16(void* lds, const void* gp) {
  __builtin_amdgcn_global_load_lds(
      (const __attribute__((address_space(1))) unsigned int*)gp,
      (__attribute__((address_space(3))) unsigned int*)lds, 16, 0, 0);
}

// ---- fused: [0,EBLK) hidden GEMM + distributed global histogram;
//             [EBLK,EBLK+TBLK) G pre-pack for 32x32x16 A-fragments.
__global__ __launch_bounds__(256, 4) void k_hidtr(const float* __restrict__ ea,
                                                  const float* __restrict__ fc1w,
                                                  const float* __restrict__ fc1b,
                                                  const float* __restrict__ fc2w,
                                                  const int* __restrict__ eidx,
                                                  int* __restrict__ cntn,
                                                  unsigned short* __restrict__ hb,
                                                  unsigned short* __restrict__ G) {
  const int bid = blockIdx.x, tid = threadIdx.x;

  if (bid >= EBLK) {           // ---- G pre-pack for 32x32x16 A-fragments
    int idx = (bid - EBLK) * 256 + tid;
    if (idx < 64 * JTOT) {
      int jt = idx >> 11;             // 2048 shorts per tile
      int r  = idx & 2047;
      int s  = r >> 9;                // sub-K (0..3)
      int l  = (r >> 3) & 63;         // lane
      int i  = r & 7;
      int j  = jt * 32 + (l & 31);
      int k  = s * 16 + (l >> 5) * 8 + i;
      G[idx] = f2bf(fc2w[k * JTOT + j]);
    }
    return;
  }

  // ---- hidden GEMM: 128 edges/block, 4 waves x 32 edges, MFMA 16x16x32 bf16
  __shared__ unsigned short T[64 * 72];    // fc1^T bf16 (9,216 B)
  __shared__ unsigned short E[128 * 72];   // ea bf16 -> h staging (18,432 B)
  __shared__ float b1s[64];
  const int e0 = bid * 128;
  if (tid < 128) {
    int e = e0 + tid;
    if (e < NEDGES) atomicAdd(&cntn[eidx[e]], 1);
  }
  if (tid < 64) b1s[tid] = fc1b[tid];
  #pragma unroll
  for (int it = 0; it < 4; it++) {
    int q = tid + 256 * it;
    int k = q >> 4, j4 = (q & 15) * 4;
    float4 v = *(const float4*)(fc1w + (size_t)q * 4);
    T[(j4+0)*72 + k] = f2bf(v.x);
    T[(j4+1)*72 + k] = f2bf(v.y);
    T[(j4+2)*72 + k] = f2bf(v.z);
    T[(j4+3)*72 + k] = f2bf(v.w);
  }
  #pragma unroll
  for (int it = 0; it < 8; it++) {
    int q = tid + 256 * it;
    int e = q >> 4, k4 = (q & 15) * 4;
    int ge = e0 + e;
    float4 v = (ge < NEDGES) ? *(const float4*)(ea + (size_t)ge * 64 + k4)
                             : make_float4(0.f, 0.f, 0.f, 0.f);
    ushort4 p;
    p.x = f2bf(v.x); p.y = f2bf(v.y); p.z = f2bf(v.z); p.w = f2bf(v.w);
    *(ushort4*)(&E[e*72 + k4]) = p;
  }
  __syncthreads();

  const int wave = tid >> 6, lane = tid & 63, col = lane & 15, rg = lane >> 4;
  short8 bf[2][2];
  #pragma unroll
  for (int nt = 0; nt < 2; nt++) {
    int er = wave*32 + nt*16 + col;
    bf[nt][0] = *(const short8*)(&E[er*72 + rg*8]);
    bf[nt][1] = *(const short8*)(&E[er*72 + 32 + rg*8]);
  }
  floatx4 acc[4][2];
  #pragma unroll
  for (int jt = 0; jt < 4; jt++) {
    int j = jt*16 + col;
    short8 a0 = *(const short8*)(&T[j*72 + rg*8]);
    short8 a1 = *(const short8*)(&T[j*72 + 32 + rg*8]);
    float4 bb = *(const float4*)(&b1s[jt*16 + rg*4]);
    #pragma unroll
    for (int nt = 0; nt < 2; nt++) {
      floatx4 c = {bb.x, bb.y, bb.z, bb.w};
      c = __builtin_amdgcn_mfma_f32_16x16x32_bf16(a0, bf[nt][0], c, 0, 0, 0);
      c = __builtin_amdgcn_mfma_f32_16x16x32_bf16(a1, bf[nt][1], c, 0, 0, 0);
      acc[jt][nt] = c;
    }
  }
  #pragma unroll
  for (int jt = 0; jt < 4; jt++)
    #pragma unroll
    for (int nt = 0; nt < 2; nt++) {
      ushort4 p;
      p.x = f2bf(mishf(acc[jt][nt][0]));
      p.y = f2bf(mishf(acc[jt][nt][1]));
      p.z = f2bf(mishf(acc[jt][nt][2]));
      p.w = f2bf(mishf(acc[jt][nt][3]));
      *(ushort4*)(&E[(wave*32 + nt*16 + col)*72 + jt*16 + rg*4]) = p;
    }
  #pragma unroll
  for (int it = 0; it < 4; it++) {
    int g = it*64 + lane;
    int r = g >> 3, c = g & 7;
    int ge = e0 + wave*32 + r;
    if (ge < NEDGES) {
      short8 v = *(const short8*)(&E[(wave*32 + r)*72 + c*8]);
      *(short8*)(hb + (size_t)ge*64 + c*8) = v;
    }
  }
}

// ---- scan: offs/cursor from cntn; zeroes sync counters
__global__ __launch_bounds__(1024) void k_scan(const int* __restrict__ cntn,
                                               int* __restrict__ offs,
                                               int* __restrict__ cursor,
                                               int* __restrict__ sync2) {
  __shared__ int ts[1024];
  int t = threadIdx.x;
  if (t < 2) sync2[t] = 0;     // gdone, flag
  int base = t * 10;
  int loc[10]; int s = 0;
  #pragma unroll
  for (int i = 0; i < 10; i++) {
    int idx = base + i;
    int v = (idx < NNODES) ? cntn[idx] : 0;
    loc[i] = s; s += v;
  }
  ts[t] = s;
  __syncthreads();
  for (int off = 1; off < 1024; off <<= 1) {
    int v = (t >= off) ? ts[t - off] : 0;
    __syncthreads();
    ts[t] += v;
    __syncthreads();
  }
  int excl = (t == 0) ? 0 : ts[t - 1];
  #pragma unroll
  for (int i = 0; i < 10; i++) {
    int idx = base + i;
    if (idx < NNODES) { int o = excl + loc[i]; offs[idx] = o; cursor[idx] = o; }
  }
  if (t == 1023) offs[NNODES] = ts[1023];
}

// ---- fused GEMM2 + tensor product, 32x32x16 MFMA. 256 thr = 4 waves x 32 edges.
// launch_bounds(256,3): 170-reg budget -- (256,4)'s 128 cap spilled ~60B/thread
// (R10: WRITE_SIZE 28->40MB). LDS allows 4 blocks/CU, regs 3 -> 3 blocks/CU.
__global__ __launch_bounds__(256, 3) void k_tp(
    const unsigned short* __restrict__ hb,
    const unsigned short* __restrict__ G,
    const float* __restrict__ fc2b,
    const int* __restrict__ eidx,
    const float* __restrict__ node_attr,
    const float* __restrict__ edge_sh,
    int* __restrict__ cursor,
    float* __restrict__ tp) {
  __shared__ short Gs[2][4096];               // 16,384 B (2 tiles/chunk)
  __shared__ unsigned short wls[4][2048];     // 16,384 B bf16 coef tables
  __shared__ float b2s[JTOT];                 //  6,400 B
  __shared__ int pos_s[4][32];                //    512 B   (total 39,680 B)
  const int tid = threadIdx.x;
  const int wave = tid >> 6, lane = tid & 63;
  for (int i = tid; i < JTOT; i += 256) b2s[i] = fc2b[i];

  const int e0w = blockIdx.x * 128 + wave * 32;
  unsigned short* Wt = &wls[wave][0];
  {
    int el = lane & 31, hh = lane >> 5;
    int e = e0w + el;
    bool valid = e < NEDGES;
    int dst = valid ? eidx[NEDGES + e] : 0;
    const float* na = node_attr + (size_t)dst * DNODE;
    if (hh == 0) {
      pos_s[wave][el] = valid ? atomicAdd(&cursor[eidx[e]], 1) : 0;
      #pragma unroll
      for (int u = 0; u < 32; u += 4) {
        float4 v = valid ? *(const float4*)(na + u) : make_float4(0.f,0.f,0.f,0.f);
        Wt[(u+0)*32 + el] = f2bf(v.x);
        Wt[(u+1)*32 + el] = f2bf(v.y);
        Wt[(u+2)*32 + el] = f2bf(v.z);
        Wt[(u+3)*32 + el] = f2bf(v.w);
      }
    } else {
      float4 sh = valid ? *(const float4*)(edge_sh + 4*(size_t)e) : make_float4(0.f,0.f,0.f,0.f);
      const float rs3 = 0.57735026918962576f;
      #pragma unroll
      for (int u = 0; u < 8; u++) {
        float v0 = valid ? na[32 + u*3 + 0] : 0.f;
        float v1 = valid ? na[32 + u*3 + 1] : 0.f;
        float v2 = valid ? na[32 + u*3 + 2] : 0.f;
        Wt[(32 + u*3 + 0)*32 + el] = f2bf(v0);
        Wt[(32 + u*3 + 1)*32 + el] = f2bf(v1);
        Wt[(32 + u*3 + 2)*32 + el] = f2bf(v2);
        Wt[(56 + u)*32 + el] = f2bf((v0*sh.y + v1*sh.z + v2*sh.w) * rs3);
      }
    }
  }

  const int col = lane & 31, h = lane >> 5;
  const int e = e0w + col;
  const bool vld = e < NEDGES;
  float sh0c, sh1c[3];
  short8 bfr[4];
  const short8 zfrag = {0,0,0,0,0,0,0,0};
  if (vld) {
    float4 sh = *(const float4*)(edge_sh + 4*(size_t)e);
    sh0c = sh.x; sh1c[0] = sh.y; sh1c[1] = sh.z; sh1c[2] = sh.w;
    const unsigned short* hp = hb + (size_t)e * 64;
    #pragma unroll
    for (int s = 0; s < 4; s++)
      bfr[s] = *(const short8*)(hp + s*16 + h*8);
  } else {
    sh0c = 0.f; sh1c[0] = sh1c[1] = sh1c[2] = 0.f;
    #pragma unroll
    for (int s = 0; s < 4; s++) bfr[s] = zfrag;
  }

  float sacc[16], vacc[12];
  #pragma unroll
  for (int i = 0; i < 16; i++) sacc[i] = 0.f;
  #pragma unroll
  for (int i = 0; i < 12; i++) vacc[i] = 0.f;

  auto stage = [&](int ch, int b) {
    const unsigned short* gsrc = G + (size_t)ch * 4096 + tid * 8;
    #pragma unroll
    for (int i = 0; i < 2; i++)
      async_ld16(&Gs[b][(i*256 + wave*64) * 8], gsrc + i*256*8);
  };

  int buf = 0;
  auto gemm_tile = [&](int jt, int t) -> floatx16 {
    const short* gb = &Gs[buf][t * 2048];
    short8 a0 = *(const short8*)(gb + lane*8);
    short8 a1 = *(const short8*)(gb + 512 + lane*8);
    short8 a2 = *(const short8*)(gb + 1024 + lane*8);
    short8 a3 = *(const short8*)(gb + 1536 + lane*8);
    floatx16 C;
    #pragma unroll
    for (int q = 0; q < 4; q++) {
      float4 b = *(const float4*)&b2s[jt*32 + 8*q + 4*h];
      C[q*4+0] = b.x; C[q*4+1] = b.y; C[q*4+2] = b.z; C[q*4+3] = b.w;
    }
    C = __builtin_amdgcn_mfma_f32_32x32x16_bf16(a0, bfr[0], C, 0, 0, 0);
    C = __builtin_amdgcn_mfma_f32_32x32x16_bf16(a1, bfr[1], C, 0, 0, 0);
    C = __builtin_amdgcn_mfma_f32_32x32x16_bf16(a2, bfr[2], C, 0, 0, 0);
    C = __builtin_amdgcn_mfma_f32_32x32x16_bf16(a3, bfr[3], C, 0, 0, 0);
    return C;
  };
  auto apply_s = [&](const floatx16& C, float cf) {        // w1/w4
    #pragma unroll
    for (int i = 0; i < 16; i++) sacc[i] = fmaf(cf, C[i], sacc[i]);
  };
  auto apply_w2 = [&](const floatx16& C, int ubase) {
    #pragma unroll
    for (int q = 0; q < 4; q++) {
      const int u = ubase + q;
      #pragma unroll
      for (int c = 0; c < 3; c++) {
        float cf = bf2f(Wt[(32 + u*3 + c)*32 + col]) * sh0c;
        #pragma unroll
        for (int r = 0; r < 4; r++)
          vacc[c*4+r] = fmaf(cf, C[q*4+r], vacc[c*4+r]);
      }
    }
  };
  auto apply_w3 = [&](const floatx16& C, int ubase) {
    #pragma unroll
    for (int q = 0; q < 4; q++) {
      float sv = bf2f(Wt[(ubase + q)*32 + col]);
      #pragma unroll
      for (int c = 0; c < 3; c++) {
        float cf = sv * sh1c[c];
        #pragma unroll
        for (int r = 0; r < 4; r++)
          vacc[c*4+r] = fmaf(cf, C[q*4+r], vacc[c*4+r]);
      }
    }
  };

  const int cc0 = blockIdx.x % 25;
  stage(cc0, 0);
  __syncthreads();

  #pragma unroll 1
  for (int cc = 0; cc < 25; cc++) {
    int c = cc0 + cc; if (c >= 25) c -= 25;
    if (cc < 24) { int cn = c + 1; if (cn >= 25) cn = 0; stage(cn, buf ^ 1); }
    const int jt0 = c * 2;
    if (jt0 < 32) {                    // w1: u = jt
      floatx16 C0 = gemm_tile(jt0, 0);
      apply_s(C0, bf2f(Wt[jt0*32 + col]) * sh0c);
      floatx16 C1 = gemm_tile(jt0 + 1, 1);
      apply_s(C1, bf2f(Wt[(jt0+1)*32 + col]) * sh0c);
    } else if (jt0 == 32) {            // w2: u = (jt-32)*4 + q
      floatx16 C0 = gemm_tile(32, 0);
      apply_w2(C0, 0);
      floatx16 C1 = gemm_tile(33, 1);
      apply_w2(C1, 4);
    } else if (jt0 < 42) {             // w3: u = (jt-34)*4 + q
      floatx16 C0 = gemm_tile(jt0, 0);
      apply_w3(C0, (jt0 - 34) * 4);
      floatx16 C1 = gemm_tile(jt0 + 1, 1);
      apply_w3(C1, (jt0 - 33) * 4);
    } else {                           // w4: u = jt-42, coef = dot[u]
      floatx16 C0 = gemm_tile(jt0, 0);
      apply_s(C0, bf2f(Wt[(56 + jt0 - 42)*32 + col]));
      floatx16 C1 = gemm_tile(jt0 + 1, 1);
      apply_s(C1, bf2f(Wt[(56 + jt0 - 41)*32 + col]));
    }
    buf ^= 1;
    __syncthreads();
  }

  // ---- epilogue: direct stores (lane-halves own disjoint wi)
  const float ascale = 0.15811388300841897f;   // 1/sqrt(40)
  if (vld) {
    float* rowp = tp + (size_t)pos_s[wave][col] * DNODE;
    #pragma unroll
    for (int q = 0; q < 4; q++) {      // out_s wi = 8q+4h+r
      float4 v = make_float4(ascale*sacc[q*4+0], ascale*sacc[q*4+1],
                             ascale*sacc[q*4+2], ascale*sacc[q*4+3]);
      *(float4*)(rowp + 8*q + 4*h) = v;
    }
    float tmp[12];                     // out_v wi = r+4h: rowp[32+(r+4h)*3+c]
    #pragma unroll
    for (int r = 0; r < 4; r++)
      #pragma unroll
      for (int c = 0; c < 3; c++) tmp[r*3 + c] = ascale * vacc[c*4 + r];
    #pragma unroll
    for (int j = 0; j < 3; j++)
      *(float4*)(rowp + 32 + 12*h + j*4) = *(float4*)&tmp[j*4];
  }
}

// ---- per-node mean + residual + BN stats + normalize (fused, spin-wait on stats).
// All 640 blocks co-resident (<= 8 blocks/CU capacity) so the spin cannot deadlock.
__global__ __launch_bounds__(256) void k_gather(const float* __restrict__ tp,
                                                const int* __restrict__ offs,
                                                const float* __restrict__ node_attr,
                                                float* __restrict__ pre,
                                                float* __restrict__ pstat,
                                                int* __restrict__ sync2,
                                                float* __restrict__ stats,
                                                const float* __restrict__ gs,
                                                const float* __restrict__ bs,
                                                const float* __restrict__ gv,
                                                float* __restrict__ out) {
  __shared__ float redS[4*64], redQ[4*64];
  __shared__ int amLast;
  int t = threadIdx.x, wave = t >> 6, lane = t & 63;
  int gw = blockIdx.x * 4 + wave;
  const int W = GBLK * 4;
  int off = (lane < DNODE) ? lane : 0;
  float ssum = 0.f, ssq = 0.f;
  for (int n = gw; n < NNODES; n += W) {
    int beg = offs[n], end = offs[n+1];
    float acc = 0.f;
    int i = beg;
    for (; i + 4 <= end; i += 4) {
      float v0 = tp[(size_t)(i+0)*DNODE + off];
      float v1 = tp[(size_t)(i+1)*DNODE + off];
      float v2 = tp[(size_t)(i+2)*DNODE + off];
      float v3 = tp[(size_t)(i+3)*DNODE + off];
      acc += (v0 + v1) + (v2 + v3);
    }
    for (; i < end; i++) acc += tp[(size_t)i*DNODE + off];
    int c = end - beg; if (c < 1) c = 1;
    float m = acc / (float)c + node_attr[(size_t)n*DNODE + off];
    if (lane < DNODE) { pre[(size_t)n*DNODE + lane] = m; ssum += m; ssq += m*m; }
  }
  redS[wave*64 + lane] = ssum;
  redQ[wave*64 + lane] = ssq;
  __syncthreads();
  if (wave == 0 && lane < DNODE) {
    float a = redS[lane] + redS[64+lane] + redS[128+lane] + redS[192+lane];
    float b = redQ[lane] + redQ[64+lane] + redQ[128+lane] + redQ[192+lane];
    pstat[(size_t)blockIdx.x*112 + lane] = a;
    pstat[(size_t)blockIdx.x*112 + 56 + lane] = b;
  }
  __syncthreads();
  if (t == 0) {
    __threadfence();
    amLast = (atomicAdd(&sync2[0], 1) == GBLK - 1) ? 1 : 0;
  }
  __syncthreads();
  if (amLast) {
    __threadfence();
    int f = t & 127, hh = t >> 7;
    float v = 0.f;
    if (f < 112) {
      #pragma unroll 8
      for (int b = hh; b < GBLK; b += 2) v += pstat[(size_t)b*112 + f];
      redS[hh*128 + f] = v;
    }
    __syncthreads();
    if (t < 112) stats[t] = redS[t] + redS[128 + t];
    __threadfence();
    __syncthreads();
    if (t == 0) atomicExch(&sync2[1], 1);
  }
  // spin until stats published (release by last block above)
  if (t == 0) {
    while (atomicAdd(&sync2[1], 0) == 0) __builtin_amdgcn_s_sleep(8);
  }
  __syncthreads();
  __threadfence();
  // per-lane normalization constants
  const float invN = 1.f / (float)NNODES;
  float mu_l = 0.f, sc_l = 0.f, ad_l = 0.f;
  if (lane < 32) {
    float mu = stats[lane] * invN;
    float var = stats[56 + lane] * invN - mu * mu;
    mu_l = mu; sc_l = rsqrtf(var + 1e-4f) * gs[lane]; ad_l = bs[lane];
  } else if (lane < DNODE) {
    int wi = (lane - 32) / 3;
    float vn = (stats[56 + 32 + wi*3] + stats[56 + 32 + wi*3 + 1] +
                stats[56 + 32 + wi*3 + 2]) * (invN / 3.f);
    sc_l = rsqrtf(vn + 1e-4f) * gv[wi];
  }
  for (int n = gw; n < NNODES; n += W) {
    if (lane < DNODE) {
      float val = pre[(size_t)n*DNODE + lane];
      out[(size_t)n*DNODE + lane] = (val - mu_l) * sc_l + ad_l;
    }
  }
}

extern "C" void kernel_launch(void* const* d_in, const int* in_sizes, int n_in,
                              void* d_out, int out_size, void* d_ws, size_t ws_size,
                              hipStream_t stream) {
  const float* node_attr = (const float*)d_in[0];
  const int*   eidx      = (const int*)d_in[1];
  const float* edge_attr = (const float*)d_in[2];
  const float* edge_sh   = (const float*)d_in[3];
  const float* fc1w      = (const float*)d_in[4];
  const float* fc1b      = (const float*)d_in[5];
  const float* fc2w      = (const float*)d_in[6];
  const float* fc2b      = (const float*)d_in[7];
  const float* gs        = (const float*)d_in[8];
  const float* bs        = (const float*)d_in[9];
  const float* gv        = (const float*)d_in[10];

  float* ws = (float*)d_ws;
  float* tp    = ws;                                    // 5,600,000
  float* pre   = ws + 5600000;                          // 560,000
  float* stats = ws + 6160000;                          // 112 (pad 128)
  float* pstat = ws + 6160128;                          // 640*112 = 71,680
  int*   cntn  = (int*)(ws + 6231808);                  // 10,000
  int*   offs  = (int*)(ws + 6241808);                  // 10,001 (pad 10,008)
  int*   cursor= (int*)(ws + 6251816);                  // 10,000
  int*   sync2 = (int*)(ws + 6261816);                  // 2 (pad 8)
  unsigned short* G  = (unsigned short*)(ws + 6261824); // 102,400 shorts (16B-aligned)
  unsigned short* hb = (unsigned short*)(ws + 6313024); // 6,400,000 shorts
  // end = 9,513,024 floats ≈ 38.1 MB

  hipMemsetAsync(cntn, 0, (size_t)10000 * 4, stream);
  k_hidtr<<<EBLK + TBLK, 256, 0, stream>>>(edge_attr, fc1w, fc1b, fc2w, eidx, cntn, hb, G);
  k_scan<<<1, 1024, 0, stream>>>(cntn, offs, cursor, sync2);
  k_tp<<<782, 256, 0, stream>>>(hb, G, fc2b, eidx, node_attr, edge_sh, cursor, tp);
  k_gather<<<GBLK, 256, 0, stream>>>(tp, offs, node_attr, pre, pstat, sync2, stats,
                                     gs, bs, gv, (float*)d_out);
}

// Round 12
// 197.559 us; speedup vs baseline: 1.5030x; 1.5030x over previous
//
#include <hip/hip_runtime.h>
#include <stdint.h>

#define NNODES 10000
#define NEDGES 100000
#define DNODE 56
#define JTOT 1600
#define EBLK 782    // hidden-GEMM blocks (128 edges each)
#define TBLK 400    // G pre-pack blocks

typedef __attribute__((ext_vector_type(8))) short short8;
typedef __attribute__((ext_vector_type(4))) float floatx4;
typedef __attribute__((ext_vector_type(16))) float floatx16;

__device__ __forceinline__ unsigned short f2bf(float f) {
  unsigned u = __float_as_uint(f);
  u = u + 0x7fffu + ((u >> 16) & 1u);
  return (unsigned short)(u >> 16);
}
__device__ __forceinline__ float bf2f(unsigned short u) {
  return __uint_as_float(((unsigned)u) << 16);
}

__device__ __forceinline__ float mishf(float x) {
  float e = __expf(x);
  float z = 1.f + e; z = z * z;
  float t = (z - 1.f) / (z + 1.f);
  t = (x > 40.f) ? 1.f : t;
  return x * t;
}

// async 16B global -> LDS; lds base wave-uniform (HW adds lane*16)
__device__ __forceinline__ void async_ld16(void* lds, const void* gp) {
  __builtin_amdgcn_global_load_lds(
      (const __attribute__((address_space(1))) unsigned int*)gp,
      (__attribute__((address_space(3))) unsigned int*)lds, 16, 0, 0);
}

// ---- fused: [0,EBLK) hidden GEMM + distributed global histogram;
//             [EBLK,EBLK+TBLK) G pre-pack for 32x32x16 A-fragments.
__global__ __launch_bounds__(256, 4) void k_hidtr(const float* __restrict__ ea,
                                                  const float* __restrict__ fc1w,
                                                  const float* __restrict__ fc1b,
                                                  const float* __restrict__ fc2w,
                                                  const int* __restrict__ eidx,
                                                  int* __restrict__ cntn,
                                                  unsigned short* __restrict__ hb,
                                                  unsigned short* __restrict__ G) {
  const int bid = blockIdx.x, tid = threadIdx.x;

  if (bid >= EBLK) {           // ---- G pre-pack for 32x32x16 A-fragments
    int idx = (bid - EBLK) * 256 + tid;
    if (idx < 64 * JTOT) {
      int jt = idx >> 11;             // 2048 shorts per tile
      int r  = idx & 2047;
      int s  = r >> 9;                // sub-K (0..3)
      int l  = (r >> 3) & 63;         // lane
      int i  = r & 7;
      int j  = jt * 32 + (l & 31);
      int k  = s * 16 + (l >> 5) * 8 + i;
      G[idx] = f2bf(fc2w[k * JTOT + j]);
    }
    return;
  }

  // ---- hidden GEMM: 128 edges/block, 4 waves x 32 edges, MFMA 16x16x32 bf16
  __shared__ unsigned short T[64 * 72];    // fc1^T bf16 (9,216 B)
  __shared__ unsigned short E[128 * 72];   // ea bf16 -> h staging (18,432 B)
  __shared__ float b1s[64];
  const int e0 = bid * 128;
  if (tid < 128) {
    int e = e0 + tid;
    if (e < NEDGES) atomicAdd(&cntn[eidx[e]], 1);
  }
  if (tid < 64) b1s[tid] = fc1b[tid];
  #pragma unroll
  for (int it = 0; it < 4; it++) {
    int q = tid + 256 * it;
    int k = q >> 4, j4 = (q & 15) * 4;
    float4 v = *(const float4*)(fc1w + (size_t)q * 4);
    T[(j4+0)*72 + k] = f2bf(v.x);
    T[(j4+1)*72 + k] = f2bf(v.y);
    T[(j4+2)*72 + k] = f2bf(v.z);
    T[(j4+3)*72 + k] = f2bf(v.w);
  }
  #pragma unroll
  for (int it = 0; it < 8; it++) {
    int q = tid + 256 * it;
    int e = q >> 4, k4 = (q & 15) * 4;
    int ge = e0 + e;
    float4 v = (ge < NEDGES) ? *(const float4*)(ea + (size_t)ge * 64 + k4)
                             : make_float4(0.f, 0.f, 0.f, 0.f);
    ushort4 p;
    p.x = f2bf(v.x); p.y = f2bf(v.y); p.z = f2bf(v.z); p.w = f2bf(v.w);
    *(ushort4*)(&E[e*72 + k4]) = p;
  }
  __syncthreads();

  const int wave = tid >> 6, lane = tid & 63, col = lane & 15, rg = lane >> 4;
  short8 bf[2][2];
  #pragma unroll
  for (int nt = 0; nt < 2; nt++) {
    int er = wave*32 + nt*16 + col;
    bf[nt][0] = *(const short8*)(&E[er*72 + rg*8]);
    bf[nt][1] = *(const short8*)(&E[er*72 + 32 + rg*8]);
  }
  floatx4 acc[4][2];
  #pragma unroll
  for (int jt = 0; jt < 4; jt++) {
    int j = jt*16 + col;
    short8 a0 = *(const short8*)(&T[j*72 + rg*8]);
    short8 a1 = *(const short8*)(&T[j*72 + 32 + rg*8]);
    float4 bb = *(const float4*)(&b1s[jt*16 + rg*4]);
    #pragma unroll
    for (int nt = 0; nt < 2; nt++) {
      floatx4 c = {bb.x, bb.y, bb.z, bb.w};
      c = __builtin_amdgcn_mfma_f32_16x16x32_bf16(a0, bf[nt][0], c, 0, 0, 0);
      c = __builtin_amdgcn_mfma_f32_16x16x32_bf16(a1, bf[nt][1], c, 0, 0, 0);
      acc[jt][nt] = c;
    }
  }
  #pragma unroll
  for (int jt = 0; jt < 4; jt++)
    #pragma unroll
    for (int nt = 0; nt < 2; nt++) {
      ushort4 p;
      p.x = f2bf(mishf(acc[jt][nt][0]));
      p.y = f2bf(mishf(acc[jt][nt][1]));
      p.z = f2bf(mishf(acc[jt][nt][2]));
      p.w = f2bf(mishf(acc[jt][nt][3]));
      *(ushort4*)(&E[(wave*32 + nt*16 + col)*72 + jt*16 + rg*4]) = p;
    }
  #pragma unroll
  for (int it = 0; it < 4; it++) {
    int g = it*64 + lane;
    int r = g >> 3, c = g & 7;
    int ge = e0 + wave*32 + r;
    if (ge < NEDGES) {
      short8 v = *(const short8*)(&E[(wave*32 + r)*72 + c*8]);
      *(short8*)(hb + (size_t)ge*64 + c*8) = v;
    }
  }
}

// ---- scan: offs/cursor from cntn (single block, proven)
__global__ __launch_bounds__(1024) void k_scan(const int* __restrict__ cntn,
                                               int* __restrict__ offs,
                                               int* __restrict__ cursor) {
  __shared__ int ts[1024];
  int t = threadIdx.x;
  int base = t * 10;
  int loc[10]; int s = 0;
  #pragma unroll
  for (int i = 0; i < 10; i++) {
    int idx = base + i;
    int v = (idx < NNODES) ? cntn[idx] : 0;
    loc[i] = s; s += v;
  }
  ts[t] = s;
  __syncthreads();
  for (int off = 1; off < 1024; off <<= 1) {
    int v = (t >= off) ? ts[t - off] : 0;
    __syncthreads();
    ts[t] += v;
    __syncthreads();
  }
  int excl = (t == 0) ? 0 : ts[t - 1];
  #pragma unroll
  for (int i = 0; i < 10; i++) {
    int idx = base + i;
    if (idx < NNODES) { int o = excl + loc[i]; offs[idx] = o; cursor[idx] = o; }
  }
  if (t == 1023) offs[NNODES] = ts[1023];
}

// ---- fused GEMM2 + tensor product, 32x32x16 MFMA. 256 thr = 4 waves x 32 edges.
// launch_bounds(256,3): 170-reg budget -- (256,4)'s 128 cap spilled ~60B/thread
// (R10: WRITE_SIZE 28->40MB). LDS allows 4 blocks/CU, regs 3 -> 3 blocks/CU.
__global__ __launch_bounds__(256, 3) void k_tp(
    const unsigned short* __restrict__ hb,
    const unsigned short* __restrict__ G,
    const float* __restrict__ fc2b,
    const int* __restrict__ eidx,
    const float* __restrict__ node_attr,
    const float* __restrict__ edge_sh,
    int* __restrict__ cursor,
    float* __restrict__ tp) {
  __shared__ short Gs[2][4096];               // 16,384 B (2 tiles/chunk)
  __shared__ unsigned short wls[4][2048];     // 16,384 B bf16 coef tables
  __shared__ float b2s[JTOT];                 //  6,400 B
  __shared__ int pos_s[4][32];                //    512 B   (total 39,680 B)
  const int tid = threadIdx.x;
  const int wave = tid >> 6, lane = tid & 63;
  for (int i = tid; i < JTOT; i += 256) b2s[i] = fc2b[i];

  const int e0w = blockIdx.x * 128 + wave * 32;
  unsigned short* Wt = &wls[wave][0];
  {
    int el = lane & 31, hh = lane >> 5;
    int e = e0w + el;
    bool valid = e < NEDGES;
    int dst = valid ? eidx[NEDGES + e] : 0;
    const float* na = node_attr + (size_t)dst * DNODE;
    if (hh == 0) {
      pos_s[wave][el] = valid ? atomicAdd(&cursor[eidx[e]], 1) : 0;
      #pragma unroll
      for (int u = 0; u < 32; u += 4) {
        float4 v = valid ? *(const float4*)(na + u) : make_float4(0.f,0.f,0.f,0.f);
        Wt[(u+0)*32 + el] = f2bf(v.x);
        Wt[(u+1)*32 + el] = f2bf(v.y);
        Wt[(u+2)*32 + el] = f2bf(v.z);
        Wt[(u+3)*32 + el] = f2bf(v.w);
      }
    } else {
      float4 sh = valid ? *(const float4*)(edge_sh + 4*(size_t)e) : make_float4(0.f,0.f,0.f,0.f);
      const float rs3 = 0.57735026918962576f;
      #pragma unroll
      for (int u = 0; u < 8; u++) {
        float v0 = valid ? na[32 + u*3 + 0] : 0.f;
        float v1 = valid ? na[32 + u*3 + 1] : 0.f;
        float v2 = valid ? na[32 + u*3 + 2] : 0.f;
        Wt[(32 + u*3 + 0)*32 + el] = f2bf(v0);
        Wt[(32 + u*3 + 1)*32 + el] = f2bf(v1);
        Wt[(32 + u*3 + 2)*32 + el] = f2bf(v2);
        Wt[(56 + u)*32 + el] = f2bf((v0*sh.y + v1*sh.z + v2*sh.w) * rs3);
      }
    }
  }

  const int col = lane & 31, h = lane >> 5;
  const int e = e0w + col;
  const bool vld = e < NEDGES;
  float sh0c, sh1c[3];
  short8 bfr[4];
  const short8 zfrag = {0,0,0,0,0,0,0,0};
  if (vld) {
    float4 sh = *(const float4*)(edge_sh + 4*(size_t)e);
    sh0c = sh.x; sh1c[0] = sh.y; sh1c[1] = sh.z; sh1c[2] = sh.w;
    const unsigned short* hp = hb + (size_t)e * 64;
    #pragma unroll
    for (int s = 0; s < 4; s++)
      bfr[s] = *(const short8*)(hp + s*16 + h*8);
  } else {
    sh0c = 0.f; sh1c[0] = sh1c[1] = sh1c[2] = 0.f;
    #pragma unroll
    for (int s = 0; s < 4; s++) bfr[s] = zfrag;
  }

  float sacc[16], vacc[12];
  #pragma unroll
  for (int i = 0; i < 16; i++) sacc[i] = 0.f;
  #pragma unroll
  for (int i = 0; i < 12; i++) vacc[i] = 0.f;

  auto stage = [&](int ch, int b) {
    const unsigned short* gsrc = G + (size_t)ch * 4096 + tid * 8;
    #pragma unroll
    for (int i = 0; i < 2; i++)
      async_ld16(&Gs[b][(i*256 + wave*64) * 8], gsrc + i*256*8);
  };

  int buf = 0;
  auto gemm_tile = [&](int jt, int t) -> floatx16 {
    const short* gb = &Gs[buf][t * 2048];
    short8 a0 = *(const short8*)(gb + lane*8);
    short8 a1 = *(const short8*)(gb + 512 + lane*8);
    short8 a2 = *(const short8*)(gb + 1024 + lane*8);
    short8 a3 = *(const short8*)(gb + 1536 + lane*8);
    floatx16 C;
    #pragma unroll
    for (int q = 0; q < 4; q++) {
      float4 b = *(const float4*)&b2s[jt*32 + 8*q + 4*h];
      C[q*4+0] = b.x; C[q*4+1] = b.y; C[q*4+2] = b.z; C[q*4+3] = b.w;
    }
    C = __builtin_amdgcn_mfma_f32_32x32x16_bf16(a0, bfr[0], C, 0, 0, 0);
    C = __builtin_amdgcn_mfma_f32_32x32x16_bf16(a1, bfr[1], C, 0, 0, 0);
    C = __builtin_amdgcn_mfma_f32_32x32x16_bf16(a2, bfr[2], C, 0, 0, 0);
    C = __builtin_amdgcn_mfma_f32_32x32x16_bf16(a3, bfr[3], C, 0, 0, 0);
    return C;
  };
  auto apply_s = [&](const floatx16& C, float cf) {        // w1/w4
    #pragma unroll
    for (int i = 0; i < 16; i++) sacc[i] = fmaf(cf, C[i], sacc[i]);
  };
  auto apply_w2 = [&](const floatx16& C, int ubase) {
    #pragma unroll
    for (int q = 0; q < 4; q++) {
      const int u = ubase + q;
      #pragma unroll
      for (int c = 0; c < 3; c++) {
        float cf = bf2f(Wt[(32 + u*3 + c)*32 + col]) * sh0c;
        #pragma unroll
        for (int r = 0; r < 4; r++)
          vacc[c*4+r] = fmaf(cf, C[q*4+r], vacc[c*4+r]);
      }
    }
  };
  auto apply_w3 = [&](const floatx16& C, int ubase) {
    #pragma unroll
    for (int q = 0; q < 4; q++) {
      float sv = bf2f(Wt[(ubase + q)*32 + col]);
      #pragma unroll
      for (int c = 0; c < 3; c++) {
        float cf = sv * sh1c[c];
        #pragma unroll
        for (int r = 0; r < 4; r++)
          vacc[c*4+r] = fmaf(cf, C[q*4+r], vacc[c*4+r]);
      }
    }
  };

  const int cc0 = blockIdx.x % 25;
  stage(cc0, 0);
  __syncthreads();

  #pragma unroll 1
  for (int cc = 0; cc < 25; cc++) {
    int c = cc0 + cc; if (c >= 25) c -= 25;
    if (cc < 24) { int cn = c + 1; if (cn >= 25) cn = 0; stage(cn, buf ^ 1); }
    const int jt0 = c * 2;
    if (jt0 < 32) {                    // w1: u = jt
      floatx16 C0 = gemm_tile(jt0, 0);
      apply_s(C0, bf2f(Wt[jt0*32 + col]) * sh0c);
      floatx16 C1 = gemm_tile(jt0 + 1, 1);
      apply_s(C1, bf2f(Wt[(jt0+1)*32 + col]) * sh0c);
    } else if (jt0 == 32) {            // w2: u = (jt-32)*4 + q
      floatx16 C0 = gemm_tile(32, 0);
      apply_w2(C0, 0);
      floatx16 C1 = gemm_tile(33, 1);
      apply_w2(C1, 4);
    } else if (jt0 < 42) {             // w3: u = (jt-34)*4 + q
      floatx16 C0 = gemm_tile(jt0, 0);
      apply_w3(C0, (jt0 - 34) * 4);
      floatx16 C1 = gemm_tile(jt0 + 1, 1);
      apply_w3(C1, (jt0 - 33) * 4);
    } else {                           // w4: u = jt-42, coef = dot[u]
      floatx16 C0 = gemm_tile(jt0, 0);
      apply_s(C0, bf2f(Wt[(56 + jt0 - 42)*32 + col]));
      floatx16 C1 = gemm_tile(jt0 + 1, 1);
      apply_s(C1, bf2f(Wt[(56 + jt0 - 41)*32 + col]));
    }
    buf ^= 1;
    __syncthreads();
  }

  // ---- epilogue: direct stores (lane-halves own disjoint wi)
  const float ascale = 0.15811388300841897f;   // 1/sqrt(40)
  if (vld) {
    float* rowp = tp + (size_t)pos_s[wave][col] * DNODE;
    #pragma unroll
    for (int q = 0; q < 4; q++) {      // out_s wi = 8q+4h+r
      float4 v = make_float4(ascale*sacc[q*4+0], ascale*sacc[q*4+1],
                             ascale*sacc[q*4+2], ascale*sacc[q*4+3]);
      *(float4*)(rowp + 8*q + 4*h) = v;
    }
    float tmp[12];                     // out_v wi = r+4h: rowp[32+(r+4h)*3+c]
    #pragma unroll
    for (int r = 0; r < 4; r++)
      #pragma unroll
      for (int c = 0; c < 3; c++) tmp[r*3 + c] = ascale * vacc[c*4 + r];
    #pragma unroll
    for (int j = 0; j < 3; j++)
      *(float4*)(rowp + 32 + 12*h + j*4) = *(float4*)&tmp[j*4];
  }
}

// ---- per-node mean + residual + BN partials (contiguous CSR rows; R8-proven)
__global__ __launch_bounds__(256) void k_gather(const float* __restrict__ tp,
                                                const int* __restrict__ offs,
                                                const float* __restrict__ node_attr,
                                                float* __restrict__ pre,
                                                float* __restrict__ pstat) {
  __shared__ float redS[4*64], redQ[4*64];
  int t = threadIdx.x, wave = t >> 6, lane = t & 63;
  int gw = blockIdx.x * 4 + wave;
  const int W = 640 * 4;
  int off = (lane < DNODE) ? lane : 0;
  float ssum = 0.f, ssq = 0.f;
  for (int n = gw; n < NNODES; n += W) {
    int beg = offs[n], end = offs[n+1];
    float acc = 0.f;
    int i = beg;
    for (; i + 4 <= end; i += 4) {
      float v0 = tp[(size_t)(i+0)*DNODE + off];
      float v1 = tp[(size_t)(i+1)*DNODE + off];
      float v2 = tp[(size_t)(i+2)*DNODE + off];
      float v3 = tp[(size_t)(i+3)*DNODE + off];
      acc += (v0 + v1) + (v2 + v3);
    }
    for (; i < end; i++) acc += tp[(size_t)i*DNODE + off];
    int c = end - beg; if (c < 1) c = 1;
    float m = acc / (float)c + node_attr[(size_t)n*DNODE + off];
    if (lane < DNODE) { pre[(size_t)n*DNODE + lane] = m; ssum += m; ssq += m*m; }
  }
  redS[wave*64 + lane] = ssum;
  redQ[wave*64 + lane] = ssq;
  __syncthreads();
  if (wave == 0 && lane < DNODE) {
    float a = redS[lane] + redS[64+lane] + redS[128+lane] + redS[192+lane];
    float b = redQ[lane] + redQ[64+lane] + redQ[128+lane] + redQ[192+lane];
    pstat[(size_t)blockIdx.x*112 + lane] = a;
    pstat[(size_t)blockIdx.x*112 + 56 + lane] = b;
  }
}

// ---- reduce 640 partials -> stats[112]
__global__ __launch_bounds__(256) void k_stats(const float* __restrict__ pstat,
                                               float* __restrict__ stats) {
  int f = blockIdx.x * 4 + (threadIdx.x >> 6);
  int lane = threadIdx.x & 63;
  float v = 0.f;
  for (int b = lane; b < 640; b += 64) v += pstat[(size_t)b*112 + f];
  #pragma unroll
  for (int o = 32; o; o >>= 1) v += __shfl_xor(v, o);
  if (lane == 0) stats[f] = v;
}

// ---- batch norm -> d_out
__global__ __launch_bounds__(256) void k_norm(const float* __restrict__ pre,
                                              const float* __restrict__ stats,
                                              const float* __restrict__ gs,
                                              const float* __restrict__ bs,
                                              const float* __restrict__ gv,
                                              float* __restrict__ out) {
  int idx = blockIdx.x * 256 + threadIdx.x;
  if (idx >= NNODES * DNODE) return;
  int n = idx / DNODE;
  int d = idx - n * DNODE;
  float val = pre[idx];
  const float invN = 1.f / (float)NNODES;
  float res;
  if (d < 32) {
    float mu = stats[d] * invN;
    float var = stats[56 + d] * invN - mu * mu;
    res = (val - mu) * rsqrtf(var + 1e-4f) * gs[d] + bs[d];
  } else {
    int wi = (d - 32) / 3;
    float vn = (stats[56 + 32 + wi*3] + stats[56 + 32 + wi*3 + 1] +
                stats[56 + 32 + wi*3 + 2]) * (invN / 3.f);
    res = val * rsqrtf(vn + 1e-4f) * gv[wi];
  }
  out[idx] = res;
}

extern "C" void kernel_launch(void* const* d_in, const int* in_sizes, int n_in,
                              void* d_out, int out_size, void* d_ws, size_t ws_size,
                              hipStream_t stream) {
  const float* node_attr = (const float*)d_in[0];
  const int*   eidx      = (const int*)d_in[1];
  const float* edge_attr = (const float*)d_in[2];
  const float* edge_sh   = (const float*)d_in[3];
  const float* fc1w      = (const float*)d_in[4];
  const float* fc1b      = (const float*)d_in[5];
  const float* fc2w      = (const float*)d_in[6];
  const float* fc2b      = (const float*)d_in[7];
  const float* gs        = (const float*)d_in[8];
  const float* bs        = (const float*)d_in[9];
  const float* gv        = (const float*)d_in[10];

  float* ws = (float*)d_ws;
  float* tp    = ws;                                    // 5,600,000
  float* pre   = ws + 5600000;                          // 560,000
  float* stats = ws + 6160000;                          // 112 (pad 128)
  float* pstat = ws + 6160128;                          // 640*112 = 71,680
  int*   cntn  = (int*)(ws + 6231808);                  // 10,000
  int*   offs  = (int*)(ws + 6241808);                  // 10,001 (pad 10,008)
  int*   cursor= (int*)(ws + 6251816);                  // 10,000
  unsigned short* G  = (unsigned short*)(ws + 6261824); // 102,400 shorts (16B-aligned)
  unsigned short* hb = (unsigned short*)(ws + 6313024); // 6,400,000 shorts
  // end = 9,513,024 floats ≈ 38.1 MB

  hipMemsetAsync(cntn, 0, (size_t)10000 * 4, stream);
  k_hidtr<<<EBLK + TBLK, 256, 0, stream>>>(edge_attr, fc1w, fc1b, fc2w, eidx, cntn, hb, G);
  k_scan<<<1, 1024, 0, stream>>>(cntn, offs, cursor);
  k_tp<<<782, 256, 0, stream>>>(hb, G, fc2b, eidx, node_attr, edge_sh, cursor, tp);
  k_gather<<<640, 256, 0, stream>>>(tp, offs, node_attr, pre, pstat);
  k_stats<<<28, 256, 0, stream>>>(pstat, stats);
  k_norm<<<(NNODES * DNODE + 255) / 256, 256, 0, stream>>>(pre, stats, gs, bs, gv, (float*)d_out);
}

// Round 13
// 196.704 us; speedup vs baseline: 1.5095x; 1.0043x over previous
//
#include <hip/hip_runtime.h>
#include <stdint.h>

#define NNODES 10000
#define NEDGES 100000
#define DNODE 56
#define JTOT 1600
#define EBLK 782    // hidden-GEMM blocks (128 edges each)
#define TBLK 500    // G pre-pack blocks (128,000 shorts)

typedef __attribute__((ext_vector_type(8))) short short8;
typedef __attribute__((ext_vector_type(4))) float floatx4;
typedef __attribute__((ext_vector_type(16))) float floatx16;

__device__ __forceinline__ unsigned short f2bf(float f) {
  unsigned u = __float_as_uint(f);
  u = u + 0x7fffu + ((u >> 16) & 1u);
  return (unsigned short)(u >> 16);
}
__device__ __forceinline__ float bf2f(unsigned short u) {
  return __uint_as_float(((unsigned)u) << 16);
}

__device__ __forceinline__ float mishf(float x) {
  float e = __expf(x);
  float z = 1.f + e; z = z * z;
  float t = (z - 1.f) / (z + 1.f);
  t = (x > 40.f) ? 1.f : t;
  return x * t;
}

// async 16B global -> LDS; lds base wave-uniform (HW adds lane*16)
__device__ __forceinline__ void async_ld16(void* lds, const void* gp) {
  __builtin_amdgcn_global_load_lds(
      (const __attribute__((address_space(1))) unsigned int*)gp,
      (__attribute__((address_space(3))) unsigned int*)lds, 16, 0, 0);
}

// ---- fused: [0,EBLK) hidden GEMM + distributed histogram; [EBLK,EBLK+TBLK) G pre-pack.
// G tiles are K=80: sub-K s=0..3 from fc2w, s=4 has k=64 column = fc2b (bias fold).
__global__ __launch_bounds__(256, 4) void k_hidtr(const float* __restrict__ ea,
                                                  const float* __restrict__ fc1w,
                                                  const float* __restrict__ fc1b,
                                                  const float* __restrict__ fc2w,
                                                  const float* __restrict__ fc2b,
                                                  const int* __restrict__ eidx,
                                                  int* __restrict__ cntn,
                                                  unsigned short* __restrict__ hb,
                                                  unsigned short* __restrict__ G) {
  const int bid = blockIdx.x, tid = threadIdx.x;

  if (bid >= EBLK) {           // ---- G pre-pack, 2560 shorts/tile (K=80)
    int idx = (bid - EBLK) * 256 + tid;
    if (idx < 80 * JTOT) {     // 128,000
      int jt = idx / 2560;
      int r  = idx - jt * 2560;
      int s  = r >> 9;                // sub-K block (0..4)
      int l  = (r >> 3) & 63;         // lane
      int i  = r & 7;
      int j  = jt * 32 + (l & 31);
      int k  = s * 16 + (l >> 5) * 8 + i;
      float v;
      if (k < 64)       v = fc2w[k * JTOT + j];
      else if (k == 64) v = fc2b[j];
      else              v = 0.f;
      G[idx] = f2bf(v);
    }
    return;
  }

  // ---- hidden GEMM: 128 edges/block, 4 waves x 32 edges, MFMA 16x16x32 bf16
  __shared__ unsigned short T[64 * 72];    // fc1^T bf16 (9,216 B)
  __shared__ unsigned short E[128 * 72];   // ea bf16 -> h staging (18,432 B)
  __shared__ float b1s[64];
  const int e0 = bid * 128;
  if (tid < 128) {
    int e = e0 + tid;
    if (e < NEDGES) atomicAdd(&cntn[eidx[e]], 1);
  }
  if (tid < 64) b1s[tid] = fc1b[tid];
  #pragma unroll
  for (int it = 0; it < 4; it++) {
    int q = tid + 256 * it;
    int k = q >> 4, j4 = (q & 15) * 4;
    float4 v = *(const float4*)(fc1w + (size_t)q * 4);
    T[(j4+0)*72 + k] = f2bf(v.x);
    T[(j4+1)*72 + k] = f2bf(v.y);
    T[(j4+2)*72 + k] = f2bf(v.z);
    T[(j4+3)*72 + k] = f2bf(v.w);
  }
  #pragma unroll
  for (int it = 0; it < 8; it++) {
    int q = tid + 256 * it;
    int e = q >> 4, k4 = (q & 15) * 4;
    int ge = e0 + e;
    float4 v = (ge < NEDGES) ? *(const float4*)(ea + (size_t)ge * 64 + k4)
                             : make_float4(0.f, 0.f, 0.f, 0.f);
    ushort4 p;
    p.x = f2bf(v.x); p.y = f2bf(v.y); p.z = f2bf(v.z); p.w = f2bf(v.w);
    *(ushort4*)(&E[e*72 + k4]) = p;
  }
  __syncthreads();

  const int wave = tid >> 6, lane = tid & 63, col = lane & 15, rg = lane >> 4;
  short8 bf[2][2];
  #pragma unroll
  for (int nt = 0; nt < 2; nt++) {
    int er = wave*32 + nt*16 + col;
    bf[nt][0] = *(const short8*)(&E[er*72 + rg*8]);
    bf[nt][1] = *(const short8*)(&E[er*72 + 32 + rg*8]);
  }
  floatx4 acc[4][2];
  #pragma unroll
  for (int jt = 0; jt < 4; jt++) {
    int j = jt*16 + col;
    short8 a0 = *(const short8*)(&T[j*72 + rg*8]);
    short8 a1 = *(const short8*)(&T[j*72 + 32 + rg*8]);
    float4 bb = *(const float4*)(&b1s[jt*16 + rg*4]);
    #pragma unroll
    for (int nt = 0; nt < 2; nt++) {
      floatx4 c = {bb.x, bb.y, bb.z, bb.w};
      c = __builtin_amdgcn_mfma_f32_16x16x32_bf16(a0, bf[nt][0], c, 0, 0, 0);
      c = __builtin_amdgcn_mfma_f32_16x16x32_bf16(a1, bf[nt][1], c, 0, 0, 0);
      acc[jt][nt] = c;
    }
  }
  #pragma unroll
  for (int jt = 0; jt < 4; jt++)
    #pragma unroll
    for (int nt = 0; nt < 2; nt++) {
      ushort4 p;
      p.x = f2bf(mishf(acc[jt][nt][0]));
      p.y = f2bf(mishf(acc[jt][nt][1]));
      p.z = f2bf(mishf(acc[jt][nt][2]));
      p.w = f2bf(mishf(acc[jt][nt][3]));
      *(ushort4*)(&E[(wave*32 + nt*16 + col)*72 + jt*16 + rg*4]) = p;
    }
  // writeout: 80 shorts/row = 10 granules; c=8 is [1,0..], c=9 zeros (K-extension)
  const short8 kone = {(short)0x3F80, 0, 0, 0, 0, 0, 0, 0};
  const short8 kzero = {0, 0, 0, 0, 0, 0, 0, 0};
  #pragma unroll
  for (int it = 0; it < 5; it++) {
    int g = it*64 + lane;
    int r = g / 10, c = g - r*10;
    int ge = e0 + wave*32 + r;
    if (ge < NEDGES) {
      short8 v;
      if (c < 8)      v = *(const short8*)(&E[(wave*32 + r)*72 + c*8]);
      else if (c == 8) v = kone;
      else            v = kzero;
      *(short8*)(hb + (size_t)ge*80 + c*8) = v;
    }
  }
}

// ---- scan: offs/cursor from cntn (single block, proven)
__global__ __launch_bounds__(1024) void k_scan(const int* __restrict__ cntn,
                                               int* __restrict__ offs,
                                               int* __restrict__ cursor) {
  __shared__ int ts[1024];
  int t = threadIdx.x;
  int base = t * 10;
  int loc[10]; int s = 0;
  #pragma unroll
  for (int i = 0; i < 10; i++) {
    int idx = base + i;
    int v = (idx < NNODES) ? cntn[idx] : 0;
    loc[i] = s; s += v;
  }
  ts[t] = s;
  __syncthreads();
  for (int off = 1; off < 1024; off <<= 1) {
    int v = (t >= off) ? ts[t - off] : 0;
    __syncthreads();
    ts[t] += v;
    __syncthreads();
  }
  int excl = (t == 0) ? 0 : ts[t - 1];
  #pragma unroll
  for (int i = 0; i < 10; i++) {
    int idx = base + i;
    if (idx < NNODES) { int o = excl + loc[i]; offs[idx] = o; cursor[idx] = o; }
  }
  if (t == 1023) offs[NNODES] = ts[1023];
}

// ---- fused GEMM2 + tensor product, 32x32x16 MFMA, K=80 (bias folded into GEMM).
// 256 thr = 4 waves x 32 edges; C-init is a hoisted zero tuple (no per-tile LDS);
// per tile: 5 A-frag ds_read_b128 (was 4+4 with b2) -> 37% less LDS traffic.
__global__ __launch_bounds__(256, 3) void k_tp(
    const unsigned short* __restrict__ hb,
    const unsigned short* __restrict__ G,
    const int* __restrict__ eidx,
    const float* __restrict__ node_attr,
    const float* __restrict__ edge_sh,
    int* __restrict__ cursor,
    float* __restrict__ tp) {
  __shared__ short Gs[2][5120];               // 20,480 B (2 K=80 tiles/chunk)
  __shared__ unsigned short wls[4][2048];     // 16,384 B bf16 coef tables
  __shared__ int pos_s[4][32];                //    512 B   (total 37,376 B)
  const int tid = threadIdx.x;
  const int wave = tid >> 6, lane = tid & 63;

  const int e0w = blockIdx.x * 128 + wave * 32;
  unsigned short* Wt = &wls[wave][0];
  {
    int el = lane & 31, hh = lane >> 5;
    int e = e0w + el;
    bool valid = e < NEDGES;
    int dst = valid ? eidx[NEDGES + e] : 0;
    const float* na = node_attr + (size_t)dst * DNODE;
    if (hh == 0) {
      pos_s[wave][el] = valid ? atomicAdd(&cursor[eidx[e]], 1) : 0;
      #pragma unroll
      for (int u = 0; u < 32; u += 4) {
        float4 v = valid ? *(const float4*)(na + u) : make_float4(0.f,0.f,0.f,0.f);
        Wt[(u+0)*32 + el] = f2bf(v.x);
        Wt[(u+1)*32 + el] = f2bf(v.y);
        Wt[(u+2)*32 + el] = f2bf(v.z);
        Wt[(u+3)*32 + el] = f2bf(v.w);
      }
    } else {
      float4 sh = valid ? *(const float4*)(edge_sh + 4*(size_t)e) : make_float4(0.f,0.f,0.f,0.f);
      const float rs3 = 0.57735026918962576f;
      #pragma unroll
      for (int u = 0; u < 8; u++) {
        float v0 = valid ? na[32 + u*3 + 0] : 0.f;
        float v1 = valid ? na[32 + u*3 + 1] : 0.f;
        float v2 = valid ? na[32 + u*3 + 2] : 0.f;
        Wt[(32 + u*3 + 0)*32 + el] = f2bf(v0);
        Wt[(32 + u*3 + 1)*32 + el] = f2bf(v1);
        Wt[(32 + u*3 + 2)*32 + el] = f2bf(v2);
        Wt[(56 + u)*32 + el] = f2bf((v0*sh.y + v1*sh.z + v2*sh.w) * rs3);
      }
    }
  }

  const int col = lane & 31, h = lane >> 5;
  const int e = e0w + col;
  const bool vld = e < NEDGES;
  float sh0c, sh1c[3];
  short8 bfr[5];
  const short8 zfrag = {0,0,0,0,0,0,0,0};
  if (vld) {
    float4 sh = *(const float4*)(edge_sh + 4*(size_t)e);
    sh0c = sh.x; sh1c[0] = sh.y; sh1c[1] = sh.z; sh1c[2] = sh.w;
    const unsigned short* hp = hb + (size_t)e * 80;
    #pragma unroll
    for (int s = 0; s < 5; s++)
      bfr[s] = *(const short8*)(hp + s*16 + h*8);
  } else {
    sh0c = 0.f; sh1c[0] = sh1c[1] = sh1c[2] = 0.f;
    #pragma unroll
    for (int s = 0; s < 5; s++) bfr[s] = zfrag;
  }

  float sacc[16], vacc[12];
  #pragma unroll
  for (int i = 0; i < 16; i++) sacc[i] = 0.f;
  #pragma unroll
  for (int i = 0; i < 12; i++) vacc[i] = 0.f;

  // stage chunk ch (2 K=80 tiles = 5120 shorts = 640 granules); 10 wave-calls
  auto stage = [&](int ch, int b) {
    const unsigned short* gsrc = G + (size_t)ch * 5120 + lane * 8;
    #pragma unroll
    for (int c = wave; c < 10; c += 4)
      async_ld16(&Gs[b][c * 512], gsrc + c * 512);
  };

  int buf = 0;
  const floatx16 CZ = {0.f,0.f,0.f,0.f,0.f,0.f,0.f,0.f,
                       0.f,0.f,0.f,0.f,0.f,0.f,0.f,0.f};
  auto gemm_tile = [&](int t) -> floatx16 {
    const short* gb = &Gs[buf][t * 2560];
    short8 a0 = *(const short8*)(gb + lane*8);
    short8 a1 = *(const short8*)(gb + 512 + lane*8);
    short8 a2 = *(const short8*)(gb + 1024 + lane*8);
    short8 a3 = *(const short8*)(gb + 1536 + lane*8);
    short8 a4 = *(const short8*)(gb + 2048 + lane*8);
    floatx16 C;
    C = __builtin_amdgcn_mfma_f32_32x32x16_bf16(a0, bfr[0], CZ, 0, 0, 0);
    C = __builtin_amdgcn_mfma_f32_32x32x16_bf16(a1, bfr[1], C, 0, 0, 0);
    C = __builtin_amdgcn_mfma_f32_32x32x16_bf16(a2, bfr[2], C, 0, 0, 0);
    C = __builtin_amdgcn_mfma_f32_32x32x16_bf16(a3, bfr[3], C, 0, 0, 0);
    C = __builtin_amdgcn_mfma_f32_32x32x16_bf16(a4, bfr[4], C, 0, 0, 0);
    return C;
  };
  auto apply_s = [&](const floatx16& C, float cf) {        // w1/w4
    #pragma unroll
    for (int i = 0; i < 16; i++) sacc[i] = fmaf(cf, C[i], sacc[i]);
  };
  auto apply_w2 = [&](const floatx16& C, int ubase) {
    #pragma unroll
    for (int q = 0; q < 4; q++) {
      const int u = ubase + q;
      #pragma unroll
      for (int c = 0; c < 3; c++) {
        float cf = bf2f(Wt[(32 + u*3 + c)*32 + col]) * sh0c;
        #pragma unroll
        for (int r = 0; r < 4; r++)
          vacc[c*4+r] = fmaf(cf, C[q*4+r], vacc[c*4+r]);
      }
    }
  };
  auto apply_w3 = [&](const floatx16& C, int ubase) {
    #pragma unroll
    for (int q = 0; q < 4; q++) {
      float sv = bf2f(Wt[(ubase + q)*32 + col]);
      #pragma unroll
      for (int c = 0; c < 3; c++) {
        float cf = sv * sh1c[c];
        #pragma unroll
        for (int r = 0; r < 4; r++)
          vacc[c*4+r] = fmaf(cf, C[q*4+r], vacc[c*4+r]);
      }
    }
  };

  const int cc0 = blockIdx.x % 25;
  stage(cc0, 0);
  __syncthreads();

  #pragma unroll 1
  for (int cc = 0; cc < 25; cc++) {
    int c = cc0 + cc; if (c >= 25) c -= 25;
    if (cc < 24) { int cn = c + 1; if (cn >= 25) cn = 0; stage(cn, buf ^ 1); }
    const int jt0 = c * 2;
    if (jt0 < 32) {                    // w1: u = jt
      floatx16 C0 = gemm_tile(0);
      apply_s(C0, bf2f(Wt[jt0*32 + col]) * sh0c);
      floatx16 C1 = gemm_tile(1);
      apply_s(C1, bf2f(Wt[(jt0+1)*32 + col]) * sh0c);
    } else if (jt0 == 32) {            // w2: u = (jt-32)*4 + q
      floatx16 C0 = gemm_tile(0);
      apply_w2(C0, 0);
      floatx16 C1 = gemm_tile(1);
      apply_w2(C1, 4);
    } else if (jt0 < 42) {             // w3: u = (jt-34)*4 + q
      floatx16 C0 = gemm_tile(0);
      apply_w3(C0, (jt0 - 34) * 4);
      floatx16 C1 = gemm_tile(1);
      apply_w3(C1, (jt0 - 33) * 4);
    } else {                           // w4: u = jt-42, coef = dot[u]
      floatx16 C0 = gemm_tile(0);
      apply_s(C0, bf2f(Wt[(56 + jt0 - 42)*32 + col]));
      floatx16 C1 = gemm_tile(1);
      apply_s(C1, bf2f(Wt[(56 + jt0 - 41)*32 + col]));
    }
    buf ^= 1;
    __syncthreads();
  }

  // ---- epilogue: direct stores (lane-halves own disjoint wi)
  const float ascale = 0.15811388300841897f;   // 1/sqrt(40)
  if (vld) {
    float* rowp = tp + (size_t)pos_s[wave][col] * DNODE;
    #pragma unroll
    for (int q = 0; q < 4; q++) {      // out_s wi = 8q+4h+r
      float4 v = make_float4(ascale*sacc[q*4+0], ascale*sacc[q*4+1],
                             ascale*sacc[q*4+2], ascale*sacc[q*4+3]);
      *(float4*)(rowp + 8*q + 4*h) = v;
    }
    float tmp[12];                     // out_v wi = r+4h: rowp[32+(r+4h)*3+c]
    #pragma unroll
    for (int r = 0; r < 4; r++)
      #pragma unroll
      for (int c = 0; c < 3; c++) tmp[r*3 + c] = ascale * vacc[c*4 + r];
    #pragma unroll
    for (int j = 0; j < 3; j++)
      *(float4*)(rowp + 32 + 12*h + j*4) = *(float4*)&tmp[j*4];
  }
}

// ---- per-node mean + residual + BN partials (contiguous CSR rows)
__global__ __launch_bounds__(256) void k_gather(const float* __restrict__ tp,
                                                const int* __restrict__ offs,
                                                const float* __restrict__ node_attr,
                                                float* __restrict__ pre,
                                                float* __restrict__ pstat) {
  __shared__ float redS[4*64], redQ[4*64];
  int t = threadIdx.x, wave = t >> 6, lane = t & 63;
  int gw = blockIdx.x * 4 + wave;
  const int W = 640 * 4;
  int off = (lane < DNODE) ? lane : 0;
  float ssum = 0.f, ssq = 0.f;
  for (int n = gw; n < NNODES; n += W) {
    int beg = offs[n], end = offs[n+1];
    float acc = 0.f;
    int i = beg;
    for (; i + 4 <= end; i += 4) {
      float v0 = tp[(size_t)(i+0)*DNODE + off];
      float v1 = tp[(size_t)(i+1)*DNODE + off];
      float v2 = tp[(size_t)(i+2)*DNODE + off];
      float v3 = tp[(size_t)(i+3)*DNODE + off];
      acc += (v0 + v1) + (v2 + v3);
    }
    for (; i < end; i++) acc += tp[(size_t)i*DNODE + off];
    int c = end - beg; if (c < 1) c = 1;
    float m = acc / (float)c + node_attr[(size_t)n*DNODE + off];
    if (lane < DNODE) { pre[(size_t)n*DNODE + lane] = m; ssum += m; ssq += m*m; }
  }
  redS[wave*64 + lane] = ssum;
  redQ[wave*64 + lane] = ssq;
  __syncthreads();
  if (wave == 0 && lane < DNODE) {
    float a = redS[lane] + redS[64+lane] + redS[128+lane] + redS[192+lane];
    float b = redQ[lane] + redQ[64+lane] + redQ[128+lane] + redQ[192+lane];
    pstat[(size_t)blockIdx.x*112 + lane] = a;
    pstat[(size_t)blockIdx.x*112 + 56 + lane] = b;
  }
}

// ---- reduce 640 partials -> stats[112]
__global__ __launch_bounds__(256) void k_stats(const float* __restrict__ pstat,
                                               float* __restrict__ stats) {
  int f = blockIdx.x * 4 + (threadIdx.x >> 6);
  int lane = threadIdx.x & 63;
  float v = 0.f;
  for (int b = lane; b < 640; b += 64) v += pstat[(size_t)b*112 + f];
  #pragma unroll
  for (int o = 32; o; o >>= 1) v += __shfl_xor(v, o);
  if (lane == 0) stats[f] = v;
}

// ---- batch norm -> d_out
__global__ __launch_bounds__(256) void k_norm(const float* __restrict__ pre,
                                              const float* __restrict__ stats,
                                              const float* __restrict__ gs,
                                              const float* __restrict__ bs,
                                              const float* __restrict__ gv,
                                              float* __restrict__ out) {
  int idx = blockIdx.x * 256 + threadIdx.x;
  if (idx >= NNODES * DNODE) return;
  int n = idx / DNODE;
  int d = idx - n * DNODE;
  float val = pre[idx];
  const float invN = 1.f / (float)NNODES;
  float res;
  if (d < 32) {
    float mu = stats[d] * invN;
    float var = stats[56 + d] * invN - mu * mu;
    res = (val - mu) * rsqrtf(var + 1e-4f) * gs[d] + bs[d];
  } else {
    int wi = (d - 32) / 3;
    float vn = (stats[56 + 32 + wi*3] + stats[56 + 32 + wi*3 + 1] +
                stats[56 + 32 + wi*3 + 2]) * (invN / 3.f);
    res = val * rsqrtf(vn + 1e-4f) * gv[wi];
  }
  out[idx] = res;
}

extern "C" void kernel_launch(void* const* d_in, const int* in_sizes, int n_in,
                              void* d_out, int out_size, void* d_ws, size_t ws_size,
                              hipStream_t stream) {
  const float* node_attr = (const float*)d_in[0];
  const int*   eidx      = (const int*)d_in[1];
  const float* edge_attr = (const float*)d_in[2];
  const float* edge_sh   = (const float*)d_in[3];
  const float* fc1w      = (const float*)d_in[4];
  const float* fc1b      = (const float*)d_in[5];
  const float* fc2w      = (const float*)d_in[6];
  const float* fc2b      = (const float*)d_in[7];
  const float* gs        = (const float*)d_in[8];
  const float* bs        = (const float*)d_in[9];
  const float* gv        = (const float*)d_in[10];

  float* ws = (float*)d_ws;
  // layout (float offsets); pre aliases the hb region (hb dead when pre is live)
  float* tp    = ws;                                    // 5,600,000
  float* stats = ws + 5600000;                          // 112 (pad 128)
  float* pstat = ws + 5600128;                          // 640*112 = 71,680
  int*   cntn  = (int*)(ws + 5671808);                  // 10,000
  int*   offs  = (int*)(ws + 5681808);                  // 10,001 (pad 10,008)
  int*   cursor= (int*)(ws + 5691816);                  // 10,000
  unsigned short* G  = (unsigned short*)(ws + 5701824); // 128,000 shorts (16B-aligned)
  unsigned short* hb = (unsigned short*)(ws + 5765824); // 8,000,000 shorts (K=80 rows)
  float* pre   = ws + 5765824;                          // 560,000 (aliases hb; safe)
  // extent = 9,765,824 floats ≈ 39.1 MB

  hipMemsetAsync(cntn, 0, (size_t)10000 * 4, stream);
  k_hidtr<<<EBLK + TBLK, 256, 0, stream>>>(edge_attr, fc1w, fc1b, fc2w, fc2b,
                                           eidx, cntn, hb, G);
  k_scan<<<1, 1024, 0, stream>>>(cntn, offs, cursor);
  k_tp<<<782, 256, 0, stream>>>(hb, G, eidx, node_attr, edge_sh, cursor, tp);
  k_gather<<<640, 256, 0, stream>>>(tp, offs, node_attr, pre, pstat);
  k_stats<<<28, 256, 0, stream>>>(pstat, stats);
  k_norm<<<(NNODES * DNODE + 255) / 256, 256, 0, stream>>>(pre, stats, gs, bs, gv, (float*)d_out);
}